// Round 11
// baseline (60.674 us; speedup 1.0000x reference)
//
#include <hip/hip_runtime.h>

#define NOKEY 0xFFFFFFFFu
#define CAPW 512   // per-wave candidate cap (l0 half-scan worst ~480; l1/l2 full ~250)

// ws layout:
//   u32 mask[10752]    bytes [0, 43008)     -- 344064 cell claim bits (memset 0)
//   f32 partials[4096] bytes [43008, 59392) -- per-wave partial sums (memset 0;
//                                              every wave writes a STRICTLY POSITIVE value,
//                                              so 0.0 is a safe "not ready" sentinel)
// absmax note: harness compares in bf16 buckets; 1 ulp @ |ref|~1.47e6 is 8192.
// absmax in {0, 8192} = f32 sum-order jitter only (threshold = 3.58 ulps). Benign.

__device__ __forceinline__ float softplusf(float x) {
    return fmaxf(x, 0.f) + log1pf(expf(-fabsf(x)));
}

__device__ __forceinline__ float seg_dist(float px, float py,
                                          float x1, float y1, float x2, float y2) {
    float vx = x2 - x1, vy = y2 - y1;
    float wx = px - x1, wy = py - y1;
    float vv = vx * vx + vy * vy + 1e-9f;
    float t = fminf(fmaxf((wx * vx + wy * vy) / vv, 0.f), 1.f);
    float dx = px - (x1 + t * vx);
    float dy = py - (y1 + t * vy);
    return sqrtf(dx * dx + dy * dy + 1e-12f);
}

__device__ __forceinline__ float clip64(float v) {
    return fminf(fmaxf(v, -64.f), 64.f);
}

// Bitonic sort of 64 u32 keys across the wave, ascending in lane order.
__device__ __forceinline__ unsigned sort64u(unsigned v, int lane) {
    #pragma unroll
    for (int k = 2; k <= 64; k <<= 1) {
        #pragma unroll
        for (int j = k >> 1; j > 0; j >>= 1) {
            unsigned o = __shfl_xor(v, j, 64);
            bool takemin = ((lane & j) == 0) == ((lane & k) == 0);
            v = (takemin ? (o < v) : (o > v)) ? o : v;
        }
    }
    return v;
}

// best (asc) + next (asc) -> smallest 64 of union, ascending.
__device__ __forceinline__ unsigned merge64u(unsigned best, unsigned next, int lane) {
    unsigned rev = __shfl(next, 63 - lane, 64);
    unsigned m = (rev < best) ? rev : best;       // bitonic
    #pragma unroll
    for (int j = 32; j > 0; j >>= 1) {
        unsigned o = __shfl_xor(m, j, 64);
        m = ((((lane & j) == 0)) ? (o < m) : (o > m)) ? o : m;
    }
    return m;
}

__global__ __launch_bounds__(256)
void fused_loss_kernel(const float* __restrict__ reg0, const float* __restrict__ obj0,
                       const float* __restrict__ cls0,
                       const float* __restrict__ reg1, const float* __restrict__ obj1,
                       const float* __restrict__ cls1,
                       const float* __restrict__ reg2, const float* __restrict__ obj2,
                       const float* __restrict__ cls2,
                       const float* __restrict__ gt,
                       unsigned int* __restrict__ mask,
                       float* __restrict__ partials,
                       float* __restrict__ out) {
    const int lane = threadIdx.x & 63;
    const int wv = threadIdx.x >> 6;

    // blocks 0..511: two l0 tasks/block, 2 waves each (phase 0/1 scan split)
    // blocks 512..1023: four l1/l2 tasks/block, 1 wave each
    int t, phase, npart;
    if (blockIdx.x < 512) { t = (blockIdx.x << 1) | (wv >> 1); phase = wv & 1; npart = 2; }
    else                  { t = 1024 + ((blockIdx.x - 512) << 2) + wv; phase = 0; npart = 1; }

    const int l = t >> 10;
    const int bg = t & 1023;
    const int b = bg >> 6, g = bg & 63;

    int Ws, HW, wshift, cellbase; float stride;
    const float* reg; const float* cls; const float* obj;
    if (l == 0)      { Ws = 128; wshift = 7; HW = 16384; stride = 8.f;  reg = reg0; cls = cls0; obj = obj0; cellbase = 0; }
    else if (l == 1) { Ws = 64;  wshift = 6; HW = 4096;  stride = 16.f; reg = reg1; cls = cls1; obj = obj1; cellbase = 262144; }
    else             { Ws = 32;  wshift = 5; HW = 1024;  stride = 32.f; reg = reg2; cls = cls2; obj = obj2; cellbase = 327680; }

    const float* G = gt + (size_t)((b * 64 + g) * 6);
    float Ax = G[0], Ay = G[1], Bx = G[2], By = G[3], Cx = G[4], Cy = G[5];

    __shared__ unsigned cand[4][CAPW];
    __shared__ unsigned pairbuf[2][64];

    // ---- hoisted dense-obj loads (latency hides under the scan) ----
    float ov0 = 0.f, ov1 = 0.f;
    bool  hv1 = false;
    if (npart == 2) {
        if (lane < 56) ov0 = obj0[t * 112 + phase * 56 + lane];   // l0: e < 114688
    } else {
        int e = t * 112 + lane;
        { const float* ob; int off;
          if (e < 262144)      { ob = obj0; off = e; }
          else if (e < 327680) { ob = obj1; off = e - 262144; }
          else                 { ob = obj2; off = e - 327680; }
          ov0 = ob[off]; }
        if (lane < 48) {
            hv1 = true;
            int e2 = e + 64;
            const float* ob; int off;
            if (e2 < 262144)      { ob = obj0; off = e2; }
            else if (e2 < 327680) { ob = obj1; off = e2 - 262144; }
            else                  { ob = obj2; off = e2 - 327680; }
            ov1 = ob[off];
        }
    }

    float inv_s = 1.f / stride;
    float xmn = fminf(Ax, fminf(Bx, Cx)) - 3.0625f;
    float xmx = fmaxf(Ax, fmaxf(Bx, Cx)) + 3.0625f;
    float ymn = fminf(Ay, fminf(By, Cy)) - 3.0625f;
    float ymx = fmaxf(Ay, fmaxf(By, Cy)) + 3.0625f;
    int w0 = max(0, (int)ceilf(xmn * inv_s - 0.5f));
    int w1 = min(Ws - 1, (int)floorf(xmx * inv_s - 0.5f));
    int h0 = max(0, (int)ceilf(ymn * inv_s - 0.5f));
    int h1 = min(Ws - 1, (int)floorf(ymx * inv_s - 0.5f));
    int bw = w1 - w0 + 1, bh = h1 - h0 + 1;

    // ---- scan: packed cell indexing via magic division, ballot-compact ----
    int count = 0;
    if (bw > 0 && bh > 0) {
        int n = bw * bh;
        unsigned M = (unsigned)((0x100000000ULL + (unsigned)bw - 1) / (unsigned)bw);
        for (int i0 = (phase << 6); i0 < n; i0 += (npart << 6)) {
            int i = i0 + lane;
            unsigned key = NOKEY;
            if (i < n) {
                int row = (int)__umulhi((unsigned)i, M);
                int w = w0 + (i - row * bw);
                int h = h0 + row;
                float px = (w + 0.5f) * stride;
                float py = (h + 0.5f) * stride;
                float d1 = (px - Bx) * (Ay - By) - (Ax - Bx) * (py - By);
                float d2 = (px - Cx) * (By - Cy) - (Bx - Cx) * (py - Cy);
                float d3 = (px - Ax) * (Cy - Ay) - (Cx - Ax) * (py - Ay);
                bool hasneg = (d1 < 0.f) || (d2 < 0.f) || (d3 < 0.f);
                bool haspos = (d1 > 0.f) || (d2 > 0.f) || (d3 > 0.f);
                bool inside = !(hasneg && haspos);
                float dist = fminf(seg_dist(px, py, Ax, Ay, Bx, By),
                             fminf(seg_dist(px, py, Bx, By, Cx, Cy),
                                   seg_dist(px, py, Cx, Cy, Ax, Ay)));
                if (inside || dist <= 3.0f)
                    key = (__float_as_uint(dist) & 0xFFFFC000u) | (unsigned)((h << wshift) + w);
            }
            unsigned long long m = __ballot(key != NOKEY);
            if (m) {
                if (key != NOKEY) {
                    int slot = count + (int)__popcll(m & ((1ull << lane) - 1ull));
                    if (slot < CAPW) cand[wv][slot] = key;
                }
                count += (int)__popcll(m);
            }
        }
        count = min(count, CAPW);
    }

    // ---- per-wave top-64 (sorted when a pair-merge will follow) ----
    unsigned best = NOKEY;
    if (npart == 1 && count <= 64) {
        if (lane < count) best = cand[wv][lane];
    } else {
        best = sort64u((lane < count) ? cand[wv][lane] : NOKEY, lane);
        int nchunks = (count + 63) >> 6;
        for (int c = 1; c < nchunks; ++c) {
            int ix = (c << 6) + lane;
            unsigned v = (ix < count) ? cand[wv][ix] : NOKEY;
            v = sort64u(v, lane);
            unsigned cmin = __shfl(v, 0, 64);
            unsigned bmax = __shfl(best, 63, 64);
            if (cmin < bmax) best = merge64u(best, v, lane);
        }
    }

    // ---- l0 pair-merge: phase-1 wave owns the final set ----
    if (npart == 2 && phase == 0) pairbuf[wv >> 1][lane] = best;
    __syncthreads();
    if (npart == 2) {
        if (phase == 1) best = merge64u(best, pairbuf[wv >> 1][lane], lane);
        else            best = NOKEY;     // phase-0 wave does no gather
    }

    // ---- per-selected-pixel losses + obj claim-correction ----
    float lsum = 0.f;
    if (best != NOKEY) {
        int pix = (int)(best & 0x3FFFu);
        int h = pix >> wshift, w = pix & (Ws - 1);
        float ax = (w + 0.5f) * stride, ay = (h + 0.5f) * stride;
        float g0x = (Ax - ax) * inv_s, g0y = (Ay - ay) * inv_s;
        float g1x = (Bx - ax) * inv_s, g1y = (By - ay) * inv_s;
        float g2x = (Cx - ax) * inv_s, g2y = (Cy - ay) * inv_s;
        const float* rb = reg + (size_t)b * 6 * HW + pix;
        float p0x = clip64(rb[0]);
        float p0y = clip64(rb[HW]);
        float p1x = clip64(rb[2 * HW]);
        float p1y = clip64(rb[3 * HW]);
        float p2x = clip64(rb[4 * HW]);
        float p2y = clip64(rb[5 * HW]);
        float lp0 = (p0x - g0x) * (p0x - g0x) + (p0y - g0y) * (p0y - g0y);
        float d11 = sqrtf((p1x - g1x) * (p1x - g1x) + (p1y - g1y) * (p1y - g1y));
        float d12 = sqrtf((p1x - g2x) * (p1x - g2x) + (p1y - g2y) * (p1y - g2y));
        float d21 = sqrtf((p2x - g1x) * (p2x - g1x) + (p2y - g1y) * (p2y - g1y));
        float d22 = sqrtf((p2x - g2x) * (p2x - g2x) + (p2y - g2y) * (p2y - g2y));
        float cd = fminf(d11, d12) + fminf(d21, d22) + fminf(d11, d21) + fminf(d12, d22);
        float x = cls[(size_t)b * HW + pix];
        lsum = lp0 + cd + softplusf(-x);

        int e = cellbase + b * HW + pix;
        unsigned bit = 1u << (e & 31);
        unsigned old = atomicOr(&mask[e >> 5], bit);
        if (!(old & bit)) {
            float ox = obj[(size_t)b * HW + pix];
            lsum += 1.2f * softplusf(-ox) - softplusf(ox);
        }
    }

    // ---- dense obj BCE from hoisted values (strictly positive contribution) ----
    if (npart == 2) {
        if (lane < 56) lsum += softplusf(ov0);
    } else {
        lsum += softplusf(ov0);
        if (hv1) lsum += softplusf(ov1);
    }

    // ---- wave reduce + agent-scope release store of the partial ----
    for (int s = 32; s; s >>= 1) lsum += __shfl_xor(lsum, s, 64);
    if (lane == 0)
        __hip_atomic_store(&partials[(blockIdx.x << 2) + wv], lsum,
                           __ATOMIC_RELEASE, __HIP_MEMORY_SCOPE_AGENT);

    // ---- spinner block: poll all 4096 partials, then final reduction ----
    if (blockIdx.x == 1023) {
        const int tid = threadIdx.x;
        float vals[16];
        for (;;) {
            bool ok = true;
            #pragma unroll
            for (int i = 0; i < 16; ++i) {
                vals[i] = __hip_atomic_load(&partials[tid + (i << 8)],
                                            __ATOMIC_ACQUIRE, __HIP_MEMORY_SCOPE_AGENT);
                ok &= (vals[i] != 0.f);
            }
            if (__syncthreads_and(ok ? 1 : 0)) break;
        }
        float s = 0.f;
        #pragma unroll
        for (int i = 0; i < 16; ++i) s += vals[i];   // fixed order: deterministic
        for (int sh = 32; sh; sh >>= 1) s += __shfl_xor(s, sh, 64);
        __shared__ float wsum[4];
        if ((tid & 63) == 0) wsum[tid >> 6] = s;
        __syncthreads();
        if (tid == 0) out[0] = wsum[0] + wsum[1] + wsum[2] + wsum[3];
    }
}

extern "C" void kernel_launch(void* const* d_in, const int* in_sizes, int n_in,
                              void* d_out, int out_size, void* d_ws, size_t ws_size,
                              hipStream_t stream) {
    const float* reg0 = (const float*)d_in[0];
    const float* obj0 = (const float*)d_in[1];
    const float* cls0 = (const float*)d_in[2];
    const float* reg1 = (const float*)d_in[3];
    const float* obj1 = (const float*)d_in[4];
    const float* cls1 = (const float*)d_in[5];
    const float* reg2 = (const float*)d_in[6];
    const float* obj2 = (const float*)d_in[7];
    const float* cls2 = (const float*)d_in[8];
    const float* gt   = (const float*)d_in[9];

    unsigned int* mask     = (unsigned int*)d_ws;
    float*        partials = (float*)((char*)d_ws + 43008);

    (void)hipMemsetAsync(d_ws, 0, 59392, stream);   // mask + partials sentinel

    fused_loss_kernel<<<1024, 256, 0, stream>>>(
        reg0, obj0, cls0, reg1, obj1, cls1, reg2, obj2, cls2, gt,
        mask, partials, (float*)d_out);
}

// Round 12
// 20.127 us; speedup vs baseline: 3.0146x; 3.0146x over previous
//
#include <hip/hip_runtime.h>

#define NOKEY 0xFFFFFFFFu
#define CAPW 512   // per-wave candidate cap (l0 half-scan worst ~480; l1/l2 full ~250)

// ws layout:
//   u32 mask[10752]    bytes [0, 43008)     -- 344064 cell claim bits (memset 0)
//   f32 partials[4096] bytes [43008, 59392) -- per-wave partial sums (all written)
// absmax note: harness compares in bf16 buckets; 1 ulp @ |ref|~1.47e6 is 8192.
// absmax in {0, 8192} = f32 sum-order jitter only (threshold = 3.58 ulps). Benign.
// Measured structural facts (R5/R8/R11): same-address atomicAdd chains and
// spin-wait completion both cost FAR more than a second graph node. Keep the
// two-kernel plain-store structure.

__device__ __forceinline__ float softplusf(float x) {
    return fmaxf(x, 0.f) + log1pf(expf(-fabsf(x)));
}

__device__ __forceinline__ float seg_dist(float px, float py,
                                          float x1, float y1, float x2, float y2) {
    float vx = x2 - x1, vy = y2 - y1;
    float wx = px - x1, wy = py - y1;
    float vv = vx * vx + vy * vy + 1e-9f;
    float t = fminf(fmaxf((wx * vx + wy * vy) / vv, 0.f), 1.f);
    float dx = px - (x1 + t * vx);
    float dy = py - (y1 + t * vy);
    return sqrtf(dx * dx + dy * dy + 1e-12f);
}

__device__ __forceinline__ float clip64(float v) {
    return fminf(fmaxf(v, -64.f), 64.f);
}

// Bitonic sort of 64 u32 keys across the wave, ascending in lane order.
__device__ __forceinline__ unsigned sort64u(unsigned v, int lane) {
    #pragma unroll
    for (int k = 2; k <= 64; k <<= 1) {
        #pragma unroll
        for (int j = k >> 1; j > 0; j >>= 1) {
            unsigned o = __shfl_xor(v, j, 64);
            bool takemin = ((lane & j) == 0) == ((lane & k) == 0);
            v = (takemin ? (o < v) : (o > v)) ? o : v;
        }
    }
    return v;
}

// best (asc) + next (asc) -> smallest 64 of union, ascending.
__device__ __forceinline__ unsigned merge64u(unsigned best, unsigned next, int lane) {
    unsigned rev = __shfl(next, 63 - lane, 64);
    unsigned m = (rev < best) ? rev : best;       // bitonic
    #pragma unroll
    for (int j = 32; j > 0; j >>= 1) {
        unsigned o = __shfl_xor(m, j, 64);
        m = ((((lane & j) == 0)) ? (o < m) : (o > m)) ? o : m;
    }
    return m;
}

__global__ __launch_bounds__(256)
void fused_loss_kernel(const float* __restrict__ reg0, const float* __restrict__ obj0,
                       const float* __restrict__ cls0,
                       const float* __restrict__ reg1, const float* __restrict__ obj1,
                       const float* __restrict__ cls1,
                       const float* __restrict__ reg2, const float* __restrict__ obj2,
                       const float* __restrict__ cls2,
                       const float* __restrict__ gt,
                       unsigned int* __restrict__ mask,
                       float* __restrict__ partials) {
    const int lane = threadIdx.x & 63;
    const int wv = threadIdx.x >> 6;

    // blocks 0..511: two l0 tasks/block, 2 waves each (phase 0/1 scan split)
    // blocks 512..1023: four l1/l2 tasks/block, 1 wave each
    int t, phase, npart;
    if (blockIdx.x < 512) { t = (blockIdx.x << 1) | (wv >> 1); phase = wv & 1; npart = 2; }
    else                  { t = 1024 + ((blockIdx.x - 512) << 2) + wv; phase = 0; npart = 1; }

    const int l = t >> 10;
    const int bg = t & 1023;
    const int b = bg >> 6, g = bg & 63;

    int Ws, HW, wshift, cellbase; float stride;
    const float* reg; const float* cls; const float* obj;
    if (l == 0)      { Ws = 128; wshift = 7; HW = 16384; stride = 8.f;  reg = reg0; cls = cls0; obj = obj0; cellbase = 0; }
    else if (l == 1) { Ws = 64;  wshift = 6; HW = 4096;  stride = 16.f; reg = reg1; cls = cls1; obj = obj1; cellbase = 262144; }
    else             { Ws = 32;  wshift = 5; HW = 1024;  stride = 32.f; reg = reg2; cls = cls2; obj = obj2; cellbase = 327680; }

    const float* G = gt + (size_t)((b * 64 + g) * 6);
    float Ax = G[0], Ay = G[1], Bx = G[2], By = G[3], Cx = G[4], Cy = G[5];

    __shared__ unsigned cand[4][CAPW];
    __shared__ unsigned pairbuf[2][64];

    // ---- hoisted dense-obj loads (HBM latency hides under the scan) ----
    float ov0 = 0.f, ov1 = 0.f;
    bool  hv1 = false;
    if (npart == 2) {
        if (lane < 56) ov0 = obj0[t * 112 + phase * 56 + lane];   // l0: e < 114688
    } else {
        int e = t * 112 + lane;
        { const float* ob; int off;
          if (e < 262144)      { ob = obj0; off = e; }
          else if (e < 327680) { ob = obj1; off = e - 262144; }
          else                 { ob = obj2; off = e - 327680; }
          ov0 = ob[off]; }
        if (lane < 48) {
            hv1 = true;
            int e2 = e + 64;
            const float* ob; int off;
            if (e2 < 262144)      { ob = obj0; off = e2; }
            else if (e2 < 327680) { ob = obj1; off = e2 - 262144; }
            else                  { ob = obj2; off = e2 - 327680; }
            ov1 = ob[off];
        }
    }

    float inv_s = 1.f / stride;
    float xmn = fminf(Ax, fminf(Bx, Cx)) - 3.0625f;
    float xmx = fmaxf(Ax, fmaxf(Bx, Cx)) + 3.0625f;
    float ymn = fminf(Ay, fminf(By, Cy)) - 3.0625f;
    float ymx = fmaxf(Ay, fmaxf(By, Cy)) + 3.0625f;
    int w0 = max(0, (int)ceilf(xmn * inv_s - 0.5f));
    int w1 = min(Ws - 1, (int)floorf(xmx * inv_s - 0.5f));
    int h0 = max(0, (int)ceilf(ymn * inv_s - 0.5f));
    int h1 = min(Ws - 1, (int)floorf(ymx * inv_s - 0.5f));
    int bw = w1 - w0 + 1, bh = h1 - h0 + 1;

    // ---- scan: packed cell indexing via magic division, ballot-compact ----
    int count = 0;
    if (bw > 0 && bh > 0) {
        int n = bw * bh;
        unsigned M = (unsigned)((0x100000000ULL + (unsigned)bw - 1) / (unsigned)bw);
        for (int i0 = (phase << 6); i0 < n; i0 += (npart << 6)) {
            int i = i0 + lane;
            unsigned key = NOKEY;
            if (i < n) {
                int row = (int)__umulhi((unsigned)i, M);
                int w = w0 + (i - row * bw);
                int h = h0 + row;
                float px = (w + 0.5f) * stride;
                float py = (h + 0.5f) * stride;
                float d1 = (px - Bx) * (Ay - By) - (Ax - Bx) * (py - By);
                float d2 = (px - Cx) * (By - Cy) - (Bx - Cx) * (py - Cy);
                float d3 = (px - Ax) * (Cy - Ay) - (Cx - Ax) * (py - Ay);
                bool hasneg = (d1 < 0.f) || (d2 < 0.f) || (d3 < 0.f);
                bool haspos = (d1 > 0.f) || (d2 > 0.f) || (d3 > 0.f);
                bool inside = !(hasneg && haspos);
                float dist = fminf(seg_dist(px, py, Ax, Ay, Bx, By),
                             fminf(seg_dist(px, py, Bx, By, Cx, Cy),
                                   seg_dist(px, py, Cx, Cy, Ax, Ay)));
                if (inside || dist <= 3.0f)
                    key = (__float_as_uint(dist) & 0xFFFFC000u) | (unsigned)((h << wshift) + w);
            }
            unsigned long long m = __ballot(key != NOKEY);
            if (m) {
                if (key != NOKEY) {
                    int slot = count + (int)__popcll(m & ((1ull << lane) - 1ull));
                    if (slot < CAPW) cand[wv][slot] = key;
                }
                count += (int)__popcll(m);
            }
        }
        count = min(count, CAPW);
    }

    // ---- per-wave top-64 (sorted when a pair-merge will follow) ----
    unsigned best = NOKEY;
    if (npart == 1 && count <= 64) {
        if (lane < count) best = cand[wv][lane];
    } else {
        best = sort64u((lane < count) ? cand[wv][lane] : NOKEY, lane);
        int nchunks = (count + 63) >> 6;
        for (int c = 1; c < nchunks; ++c) {
            int ix = (c << 6) + lane;
            unsigned v = (ix < count) ? cand[wv][ix] : NOKEY;
            v = sort64u(v, lane);
            unsigned cmin = __shfl(v, 0, 64);
            unsigned bmax = __shfl(best, 63, 64);
            if (cmin < bmax) best = merge64u(best, v, lane);
        }
    }

    // ---- l0 pair-merge: phase-1 wave owns the final set ----
    if (npart == 2 && phase == 0) pairbuf[wv >> 1][lane] = best;
    __syncthreads();
    if (npart == 2) {
        if (phase == 1) best = merge64u(best, pairbuf[wv >> 1][lane], lane);
        else            best = NOKEY;     // phase-0 wave does no gather
    }

    // ---- per-selected-pixel losses + obj claim-correction ----
    float lsum = 0.f;
    if (best != NOKEY) {
        int pix = (int)(best & 0x3FFFu);
        int h = pix >> wshift, w = pix & (Ws - 1);
        float ax = (w + 0.5f) * stride, ay = (h + 0.5f) * stride;
        float g0x = (Ax - ax) * inv_s, g0y = (Ay - ay) * inv_s;
        float g1x = (Bx - ax) * inv_s, g1y = (By - ay) * inv_s;
        float g2x = (Cx - ax) * inv_s, g2y = (Cy - ay) * inv_s;
        const float* rb = reg + (size_t)b * 6 * HW + pix;
        float p0x = clip64(rb[0]);
        float p0y = clip64(rb[HW]);
        float p1x = clip64(rb[2 * HW]);
        float p1y = clip64(rb[3 * HW]);
        float p2x = clip64(rb[4 * HW]);
        float p2y = clip64(rb[5 * HW]);
        float lp0 = (p0x - g0x) * (p0x - g0x) + (p0y - g0y) * (p0y - g0y);
        float d11 = sqrtf((p1x - g1x) * (p1x - g1x) + (p1y - g1y) * (p1y - g1y));
        float d12 = sqrtf((p1x - g2x) * (p1x - g2x) + (p1y - g2y) * (p1y - g2y));
        float d21 = sqrtf((p2x - g1x) * (p2x - g1x) + (p2y - g1y) * (p2y - g1y));
        float d22 = sqrtf((p2x - g2x) * (p2x - g2x) + (p2y - g2y) * (p2y - g2y));
        float cd = fminf(d11, d12) + fminf(d21, d22) + fminf(d11, d21) + fminf(d12, d22);
        float x = cls[(size_t)b * HW + pix];
        lsum = lp0 + cd + softplusf(-x);

        int e = cellbase + b * HW + pix;
        unsigned bit = 1u << (e & 31);
        unsigned old = atomicOr(&mask[e >> 5], bit);
        if (!(old & bit)) {
            float ox = obj[(size_t)b * HW + pix];
            lsum += 1.2f * softplusf(-ox) - softplusf(ox);
        }
    }

    // ---- dense obj BCE from hoisted values ----
    if (npart == 2) {
        if (lane < 56) lsum += softplusf(ov0);
    } else {
        lsum += softplusf(ov0);
        if (hv1) lsum += softplusf(ov1);
    }

    // ---- wave reduce + plain store (no same-address atomics) ----
    for (int s = 32; s; s >>= 1) lsum += __shfl_xor(lsum, s, 64);
    if (lane == 0) partials[(blockIdx.x << 2) + wv] = lsum;
}

__global__ __launch_bounds__(256)
void reduce_kernel(const float* __restrict__ partials, float* __restrict__ out) {
    const int tid = threadIdx.x;
    const int lane = tid & 63;
    const int wv = tid >> 6;
    const float4* p4 = (const float4*)partials;   // 1024 float4s
    float s = 0.f;
    #pragma unroll
    for (int i = 0; i < 4; ++i) {
        float4 v = p4[tid + (i << 8)];
        s += v.x + v.y + v.z + v.w;
    }
    for (int sh = 32; sh; sh >>= 1) s += __shfl_xor(s, sh, 64);
    __shared__ float wsum[4];
    if (lane == 0) wsum[wv] = s;
    __syncthreads();
    if (tid == 0) *out = wsum[0] + wsum[1] + wsum[2] + wsum[3];
}

extern "C" void kernel_launch(void* const* d_in, const int* in_sizes, int n_in,
                              void* d_out, int out_size, void* d_ws, size_t ws_size,
                              hipStream_t stream) {
    const float* reg0 = (const float*)d_in[0];
    const float* obj0 = (const float*)d_in[1];
    const float* cls0 = (const float*)d_in[2];
    const float* reg1 = (const float*)d_in[3];
    const float* obj1 = (const float*)d_in[4];
    const float* cls1 = (const float*)d_in[5];
    const float* reg2 = (const float*)d_in[6];
    const float* obj2 = (const float*)d_in[7];
    const float* cls2 = (const float*)d_in[8];
    const float* gt   = (const float*)d_in[9];

    unsigned int* mask     = (unsigned int*)d_ws;
    float*        partials = (float*)((char*)d_ws + 43008);

    (void)hipMemsetAsync(d_ws, 0, 43008, stream);

    fused_loss_kernel<<<1024, 256, 0, stream>>>(
        reg0, obj0, cls0, reg1, obj1, cls1, reg2, obj2, cls2, gt,
        mask, partials);
    reduce_kernel<<<1, 256, 0, stream>>>(partials, (float*)d_out);
}